// Round 5
// baseline (271.902 us; speedup 1.0000x reference)
//
#include <hip/hip_runtime.h>

typedef __bf16 bf16x8 __attribute__((ext_vector_type(8)));
typedef float f32x4 __attribute__((ext_vector_type(4)));
typedef unsigned short us8 __attribute__((ext_vector_type(8)));

#define GAS __attribute__((address_space(1)))
#define LAS __attribute__((address_space(3)))

__device__ __forceinline__ unsigned short f32_to_bf16(float f) {
    unsigned int u = __float_as_uint(f);
    u += 0x7FFFu + ((u >> 16) & 1u);   // round-to-nearest-even
    return (unsigned short)(u >> 16);
}

__device__ __forceinline__ float bf16_to_f32(unsigned short h) {
    return __uint_as_float((unsigned int)h << 16);
}

__device__ __forceinline__ void load16(const unsigned short* g, unsigned short* l) {
    // async global->LDS, 16B per lane; LDS dest is wave-uniform base + lane*16
    __builtin_amdgcn_global_load_lds((GAS unsigned int*)g, (LAS unsigned int*)l, 16, 0, 0);
}

// ---------------------------------------------------------------------------
// prep (1024 threads): blocks [0,1536) convert x fp32->bf16 float4-wide;
// blocks [1536,3264) transpose the three 768x768 weights to bf16;
// block 3264 zeroes lsum[2*4096] (denominator accumulators).
// ---------------------------------------------------------------------------
__global__ __launch_bounds__(1024) void prep(
    const float* __restrict__ x, unsigned short* __restrict__ Xbf,
    const float* __restrict__ W0, const float* __restrict__ W1, const float* __restrict__ W2,
    unsigned short* __restrict__ T0, unsigned short* __restrict__ T1, unsigned short* __restrict__ T2,
    float* __restrict__ lsum)
{
    __shared__ float tile[32][33];
    const int id = blockIdx.x;
    const int t = threadIdx.x;
    if (id < 1536) {
        int i = id * 1024 + t;
        float4 v = ((const float4*)x)[i];
        ushort4 o;
        o.x = f32_to_bf16(v.x); o.y = f32_to_bf16(v.y);
        o.z = f32_to_bf16(v.z); o.w = f32_to_bf16(v.w);
        ((ushort4*)Xbf)[i] = o;
    } else if (id < 3264) {
        const int tid = id - 1536;               // 0..1727
        const int z = tid / 576, rem = tid % 576;
        const int by = rem / 24, bx = rem % 24;
        const float* W = (z == 0) ? W0 : (z == 1) ? W1 : W2;
        unsigned short* T = (z == 0) ? T0 : (z == 1) ? T1 : T2;
        const int r0 = by * 32, c0 = bx * 32;
        const int tx = t & 31, ty = t >> 5;      // 32x32
        tile[ty][tx] = W[(size_t)(r0 + ty) * 768 + c0 + tx];
        __syncthreads();
        T[(size_t)(c0 + ty) * 768 + r0 + tx] = f32_to_bf16(tile[tx][ty]);
    } else {
        float4 z4 = {0.f, 0.f, 0.f, 0.f};
        ((float4*)lsum)[t] = z4;
        ((float4*)lsum)[t + 1024] = z4;          // 8192 floats total
    }
}

// ---------------------------------------------------------------------------
// Combined Q/K/V projection (m97 structure + XOR bank-swizzle), one launch:
//   id <  768 : QK  -- C[z] = Xbf[8192,768] . (W^T[z])^T, z = id/384
//   id >= 768 : V^T -- Vt   = WvT[768,768]  . Xbf^T  -> [768, 8192]
// Weight transposes are contiguous: Wt + z*589824. Q,K contiguous: QK + z*6291456.
// ---------------------------------------------------------------------------
__global__ __launch_bounds__(256) void qkv_proj(
    const unsigned short* __restrict__ Xbf,
    const unsigned short* __restrict__ Wt,
    unsigned short* __restrict__ QK,
    unsigned short* __restrict__ Vt)
{
    const int id = blockIdx.x;
    const unsigned short* A; const unsigned short* B;
    unsigned short* C; int ldc, m0, n0;
    if (id < 768) {
        const int z = id / 384, r = id % 384;
        A = Xbf; B = Wt + (size_t)z * 589824; C = QK + (size_t)z * 6291456;
        ldc = 768;
        m0 = (r / 6) * 128; n0 = (r % 6) * 128;
    } else {
        const int j = id - 768;
        A = Wt + 1179648ull;   // WvT
        B = Xbf; C = Vt;
        ldc = 8192;
        m0 = (j >> 6) * 128; n0 = (j & 63) * 128;
    }
    const int lda = 768, ldb = 768;
    const int t = threadIdx.x;
    const int lane = t & 63;
    const int w = t >> 6;
    const int wm = (w >> 1) * 64;
    const int wn = (w & 1) * 64;

    __shared__ unsigned short At[128 * 64];
    __shared__ unsigned short Bt[128 * 64];

    f32x4 acc[4][4];
#pragma unroll
    for (int i = 0; i < 4; ++i)
#pragma unroll
        for (int j2 = 0; j2 < 4; ++j2) acc[i][j2] = (f32x4){0.f, 0.f, 0.f, 0.f};

    const int r15 = lane & 15;
    const int qa = lane >> 4;

    for (int k0 = 0; k0 < 768; k0 += 64) {
#pragma unroll
        for (int i = 0; i < 4; ++i) {
            const int c = i * 256 + t;
            const int row = c >> 3;
            const int cc = (c & 7) ^ (row & 7);
            load16(A + (size_t)(m0 + row) * lda + k0 + cc * 8, &At[c * 8]);
            load16(B + (size_t)(n0 + row) * ldb + k0 + cc * 8, &Bt[c * 8]);
        }
        __syncthreads();

#pragma unroll
        for (int ks = 0; ks < 2; ++ks) {
            bf16x8 af[4], bf[4];
#pragma unroll
            for (int mi = 0; mi < 4; ++mi) {
                const int row = wm + mi * 16 + r15;
                af[mi] = *(const bf16x8*)&At[row * 64 + (((ks << 2) + qa) ^ (row & 7)) * 8];
            }
#pragma unroll
            for (int ni = 0; ni < 4; ++ni) {
                const int row = wn + ni * 16 + r15;
                bf[ni] = *(const bf16x8*)&Bt[row * 64 + (((ks << 2) + qa) ^ (row & 7)) * 8];
            }
#pragma unroll
            for (int mi = 0; mi < 4; ++mi)
#pragma unroll
                for (int ni = 0; ni < 4; ++ni)
                    acc[mi][ni] = __builtin_amdgcn_mfma_f32_16x16x32_bf16(
                        af[mi], bf[ni], acc[mi][ni], 0, 0, 0);
        }
        __syncthreads();
    }

    const int cr = (lane >> 4) * 4;
#pragma unroll
    for (int mi = 0; mi < 4; ++mi)
#pragma unroll
        for (int ni = 0; ni < 4; ++ni) {
            const int gm = m0 + wm + mi * 16 + cr;
            const int gn = n0 + wn + ni * 16 + r15;
#pragma unroll
            for (int r = 0; r < 4; ++r)
                C[(size_t)(gm + r) * ldc + gn] = f32_to_bf16(acc[mi][ni][r]);
        }
}

// ---------------------------------------------------------------------------
// Sexp = exp(alpha * Q.K^T) bf16, 256^2 v4 core (monolithic body, ring-2 LDS,
// counted vmcnt, 2 barriers/tile, XCD swizzle). NEW: epilogue also reduces
// row sums of exp (f32, pre-rounding) and atomicAdds into lsum[batch][row]
// -- replaces the separate denominator pass.
// ---------------------------------------------------------------------------
__global__ __launch_bounds__(512, 2) void gemm_s_exp2(
    const unsigned short* __restrict__ Q, const unsigned short* __restrict__ Kb,
    unsigned short* __restrict__ Sexp, float* __restrict__ lsum, float alpha)
{
    const int f = blockIdx.x;            // 0..511
    const int xcd = f & 7;
    const int local = f >> 3;            // 0..63
    const int x = (xcd & 1) * 8 + (local & 7);
    const int y = ((xcd >> 1) & 1) * 8 + (local >> 3);
    const int bb = xcd >> 2;
    const unsigned short* A = Q + (size_t)bb * 3145728;
    const unsigned short* B = Kb + (size_t)bb * 3145728;
    unsigned short* C = Sexp + (size_t)bb * 16777216;
    float* ls = lsum + bb * 4096;
    const int m0 = y * 256, n0 = x * 256;
    const int lda = 768, ldb = 768, ldc = 4096;
    constexpr int NT = 12;

    __shared__ unsigned short As[2][256 * 64];
    __shared__ unsigned short Bs[2][256 * 64];

    const int t = threadIdx.x;          // 0..511
    const int lane = t & 63;
    const int w = t >> 6;               // 0..7
    const int wm = (w >> 2) * 128;      // 0 / 128
    const int wn = (w & 3) * 64;        // 0..192
    const int r15 = lane & 15;
    const int qa = lane >> 4;           // 0..3

    const unsigned short* srcA[4];
    const unsigned short* srcB[4];
    int dst[4];
#pragma unroll
    for (int i = 0; i < 4; ++i) {
        const int c = i * 512 + t;
        const int row = c >> 3;
        const int cc = (c & 7) ^ (row & 7);
        srcA[i] = A + (size_t)(m0 + row) * lda + cc * 8;
        srcB[i] = B + (size_t)(n0 + row) * ldb + cc * 8;
        dst[i] = c * 8;
    }

    auto stage = [&](int buf, int kbase) {
#pragma unroll
        for (int i = 0; i < 4; ++i)
            load16(srcA[i] + kbase, &As[buf][dst[i]]);
#pragma unroll
        for (int i = 0; i < 4; ++i)
            load16(srcB[i] + kbase, &Bs[buf][dst[i]]);
    };

    int offA[8][2], offB[4][2];
#pragma unroll
    for (int mi = 0; mi < 8; ++mi) {
        const int row = wm + mi * 16 + r15;
#pragma unroll
        for (int ks = 0; ks < 2; ++ks)
            offA[mi][ks] = row * 64 + (((ks << 2) + qa) ^ (row & 7)) * 8;
    }
#pragma unroll
    for (int ni = 0; ni < 4; ++ni) {
        const int row = wn + ni * 16 + r15;
#pragma unroll
        for (int ks = 0; ks < 2; ++ks)
            offB[ni][ks] = row * 64 + (((ks << 2) + qa) ^ (row & 7)) * 8;
    }

    f32x4 acc[8][4];
#pragma unroll
    for (int i = 0; i < 8; ++i)
#pragma unroll
        for (int j = 0; j < 4; ++j) acc[i][j] = (f32x4){0.f, 0.f, 0.f, 0.f};

    stage(0, 0);
    stage(1, 64);

    for (int tt = 0; tt < NT; ++tt) {
        const int b = tt & 1;
        if (tt == NT - 1) {
            asm volatile("s_waitcnt vmcnt(0)" ::: "memory");
        } else {
            asm volatile("s_waitcnt vmcnt(8)" ::: "memory");
        }
        __builtin_amdgcn_s_barrier();

#pragma unroll
        for (int ks = 0; ks < 2; ++ks) {
            bf16x8 aA[8], bB[4];
#pragma unroll
            for (int i = 0; i < 8; ++i)
                aA[i] = *(const bf16x8*)&As[b][offA[i][ks]];
#pragma unroll
            for (int ni = 0; ni < 4; ++ni)
                bB[ni] = *(const bf16x8*)&Bs[b][offB[ni][ks]];
#pragma unroll
            for (int i = 0; i < 8; ++i)
#pragma unroll
                for (int ni = 0; ni < 4; ++ni)
                    acc[i][ni] = __builtin_amdgcn_mfma_f32_16x16x32_bf16(
                        aA[i], bB[ni], acc[i][ni], 0, 0, 0);
        }

        asm volatile("" ::: "memory");
        __builtin_amdgcn_s_barrier();

        if (tt + 2 < NT) stage(b, (tt + 2) << 6);
    }

    // epilogue: exp + store bf16 + per-row f32 sums (16-lane shfl reduce ->
    // one atomicAdd per row-segment). C/D layout col=lane&15, row=(lane>>4)*4+reg.
    const int cr = (lane >> 4) * 4;
#pragma unroll
    for (int mi = 0; mi < 8; ++mi) {
        const int gm = m0 + wm + mi * 16 + cr;
        float rs0 = 0.f, rs1 = 0.f, rs2 = 0.f, rs3 = 0.f;
#pragma unroll
        for (int ni = 0; ni < 4; ++ni) {
            const int gn = n0 + wn + ni * 16 + r15;
            float v0 = __expf(alpha * acc[mi][ni][0]);
            float v1 = __expf(alpha * acc[mi][ni][1]);
            float v2 = __expf(alpha * acc[mi][ni][2]);
            float v3 = __expf(alpha * acc[mi][ni][3]);
            C[(size_t)(gm + 0) * ldc + gn] = f32_to_bf16(v0);
            C[(size_t)(gm + 1) * ldc + gn] = f32_to_bf16(v1);
            C[(size_t)(gm + 2) * ldc + gn] = f32_to_bf16(v2);
            C[(size_t)(gm + 3) * ldc + gn] = f32_to_bf16(v3);
            rs0 += v0; rs1 += v1; rs2 += v2; rs3 += v3;
        }
#pragma unroll
        for (int m = 1; m < 16; m <<= 1) {
            rs0 += __shfl_xor(rs0, m, 64);
            rs1 += __shfl_xor(rs1, m, 64);
            rs2 += __shfl_xor(rs2, m, 64);
            rs3 += __shfl_xor(rs3, m, 64);
        }
        if (r15 == 0) {
            atomicAdd(&ls[gm + 0], rs0);
            atomicAdd(&ls[gm + 1], rs1);
            atomicAdd(&ls[gm + 2], rs2);
            atomicAdd(&ls[gm + 3], rs3);
        }
    }
}

// ---------------------------------------------------------------------------
// Fused O-GEMM + normalize: out = (Sexp . V) / lsum, fp32, single K=4096
// chain (no split, no partials). BM=128 x BN=192 -> 2x32x4 = 256 blocks =
// exact one round. Ring-3 LDS (120 KiB), counted vmcnt(10/5/0).
// 8 waves 2M x 4N, per-wave 64x48 (acc[4][3]).
// XCD swizzle: xcd = batch*4 + n -> each XCD keeps ONE V^T panel (1.5 MB)
// L2-resident while streaming Sexp rows.
// ---------------------------------------------------------------------------
__global__ __launch_bounds__(512, 2) void gemm_out(
    const unsigned short* __restrict__ P, const unsigned short* __restrict__ Vt,
    const float* __restrict__ lsum, float* __restrict__ out)
{
    const int f = blockIdx.x;           // 0..255
    const int xcd = f & 7;
    const int batch = xcd >> 2;
    const int nb = xcd & 3;
    const int mb = f >> 3;              // 0..31
    const unsigned short* A = P + (size_t)batch * 16777216;
    const unsigned short* B = Vt + (size_t)batch * 4096;
    const float* ls = lsum + batch * 4096;
    float* C = out + (size_t)batch * 3145728;
    const int m0 = mb * 128, n0 = nb * 192;
    const int lda = 4096, ldb = 8192;
    constexpr int NT = 64;

    __shared__ unsigned short As[3][128 * 64];
    __shared__ unsigned short Bs[3][192 * 64];

    const int t = threadIdx.x;          // 0..511
    const int lane = t & 63;
    const int w = t >> 6;               // 0..7
    const int wm = (w >> 2) * 64;       // 0 / 64
    const int wn = (w & 3) * 48;        // 0..144
    const int r15 = lane & 15;
    const int qa = lane >> 4;           // 0..3

    // staging: A 1024 chunks -> 2/thread ; B 1536 chunks -> 3/thread
    const unsigned short* srcA[2];
    int dstA[2];
#pragma unroll
    for (int i = 0; i < 2; ++i) {
        const int c = i * 512 + t;
        const int row = c >> 3;
        const int cc = (c & 7) ^ (row & 7);
        srcA[i] = A + (size_t)(m0 + row) * lda + cc * 8;
        dstA[i] = c * 8;
    }
    const unsigned short* srcB[3];
    int dstB[3];
#pragma unroll
    for (int i = 0; i < 3; ++i) {
        const int c = i * 512 + t;
        const int row = c >> 3;
        const int cc = (c & 7) ^ (row & 7);
        srcB[i] = B + (size_t)(n0 + row) * ldb + cc * 8;
        dstB[i] = c * 8;
    }

    auto stage = [&](int buf, int kbase) {
#pragma unroll
        for (int i = 0; i < 2; ++i)
            load16(srcA[i] + kbase, &As[buf][dstA[i]]);
#pragma unroll
        for (int i = 0; i < 3; ++i)
            load16(srcB[i] + kbase, &Bs[buf][dstB[i]]);
    };

    int offA[4][2], offB[3][2];
#pragma unroll
    for (int mi = 0; mi < 4; ++mi) {
        const int row = wm + mi * 16 + r15;
#pragma unroll
        for (int ks = 0; ks < 2; ++ks)
            offA[mi][ks] = row * 64 + (((ks << 2) + qa) ^ (row & 7)) * 8;
    }
#pragma unroll
    for (int ni = 0; ni < 3; ++ni) {
        const int row = wn + ni * 16 + r15;
#pragma unroll
        for (int ks = 0; ks < 2; ++ks)
            offB[ni][ks] = row * 64 + (((ks << 2) + qa) ^ (row & 7)) * 8;
    }

    f32x4 acc[4][3];
#pragma unroll
    for (int i = 0; i < 4; ++i)
#pragma unroll
        for (int j = 0; j < 3; ++j) acc[i][j] = (f32x4){0.f, 0.f, 0.f, 0.f};

    stage(0, 0);
    stage(1, 64);
    stage(2, 128);

    int b = 0;
    for (int tt = 0; tt < NT; ++tt) {
        if (tt < NT - 2) {
            asm volatile("s_waitcnt vmcnt(10)" ::: "memory");
        } else if (tt == NT - 2) {
            asm volatile("s_waitcnt vmcnt(5)" ::: "memory");
        } else {
            asm volatile("s_waitcnt vmcnt(0)" ::: "memory");
        }
        __builtin_amdgcn_s_barrier();

#pragma unroll
        for (int ks = 0; ks < 2; ++ks) {
            bf16x8 aA[4], bB[3];
#pragma unroll
            for (int i = 0; i < 4; ++i)
                aA[i] = *(const bf16x8*)&As[b][offA[i][ks]];
#pragma unroll
            for (int ni = 0; ni < 3; ++ni)
                bB[ni] = *(const bf16x8*)&Bs[b][offB[ni][ks]];
#pragma unroll
            for (int i = 0; i < 4; ++i)
#pragma unroll
                for (int ni = 0; ni < 3; ++ni)
                    acc[i][ni] = __builtin_amdgcn_mfma_f32_16x16x32_bf16(
                        aA[i], bB[ni], acc[i][ni], 0, 0, 0);
        }

        asm volatile("" ::: "memory");
        __builtin_amdgcn_s_barrier();

        if (tt + 3 < NT) stage(b, (tt + 3) << 6);
        b = (b == 2) ? 0 : b + 1;
    }

    // epilogue: divide by denominator, write fp32 out
    const int cr = (lane >> 4) * 4;
#pragma unroll
    for (int mi = 0; mi < 4; ++mi) {
        const int gm = m0 + wm + mi * 16 + cr;
        const float i0 = 1.f / ls[gm + 0];
        const float i1 = 1.f / ls[gm + 1];
        const float i2 = 1.f / ls[gm + 2];
        const float i3 = 1.f / ls[gm + 3];
#pragma unroll
        for (int ni = 0; ni < 3; ++ni) {
            const int gn = n0 + wn + ni * 16 + r15;
            C[(size_t)(gm + 0) * 768 + gn] = acc[mi][ni][0] * i0;
            C[(size_t)(gm + 1) * 768 + gn] = acc[mi][ni][1] * i1;
            C[(size_t)(gm + 2) * 768 + gn] = acc[mi][ni][2] * i2;
            C[(size_t)(gm + 3) * 768 + gn] = acc[mi][ni][3] * i3;
        }
    }
}

// ---------------------------------------------------------------------------
extern "C" void kernel_launch(void* const* d_in, const int* in_sizes, int n_in,
                              void* d_out, int out_size, void* d_ws, size_t ws_size,
                              hipStream_t stream) {
    const float* x  = (const float*)d_in[0];   // [2,4096,768]
    const float* Wq = (const float*)d_in[1];   // [768,768]
    const float* Wk = (const float*)d_in[2];
    const float* Wv = (const float*)d_in[3];
    float* out = (float*)d_out;                // [2,4096,768] fp32

    char* base = (char*)d_ws;
    size_t off = 0;
    auto alloc = [&](size_t b) { char* p = base + off; off += (b + 255) & ~(size_t)255; return p; };

    unsigned short* Xbf = (unsigned short*)alloc(8192ull * 768 * 2);   // x as bf16
    unsigned short* WqT = (unsigned short*)alloc(768ull * 768 * 2);    // W^T bf16, x3 contiguous
    unsigned short* WkT = (unsigned short*)alloc(768ull * 768 * 2);
    unsigned short* WvT = (unsigned short*)alloc(768ull * 768 * 2);
    unsigned short* Qb  = (unsigned short*)alloc(8192ull * 768 * 2);   // Q,K bf16, contiguous
    unsigned short* Kb  = (unsigned short*)alloc(8192ull * 768 * 2);
    unsigned short* Vt  = (unsigned short*)alloc(768ull * 8192 * 2);   // V^T bf16 [768,8192]
    unsigned short* Sexp = (unsigned short*)alloc(2ull * 4096 * 4096 * 2); // exp(scores) bf16
    float* lsum = (float*)alloc(2ull * 4096 * 4);                      // softmax denominators
    (void)ws_size; (void)in_sizes; (void)n_in; (void)out_size; (void)WkT; (void)WvT;

    // 1) x -> bf16, W -> W^T bf16, lsum <- 0
    prep<<<dim3(3265), dim3(1024), 0, stream>>>(x, Xbf, Wq, Wk, Wv, WqT, WkT, WvT, lsum);
    // 2) Q, K and V^T in ONE launch (1152 blocks)
    qkv_proj<<<dim3(1152), dim3(256), 0, stream>>>(Xbf, WqT, Qb, Vt);
    // 3) Sexp = exp(Q.K^T / sqrt(768)) bf16 + fused row-sum atomics
    gemm_s_exp2<<<dim3(512), dim3(512), 0, stream>>>(
        Qb, Kb, Sexp, lsum, 0.03608439182435161f);
    // 4) out = (Sexp . V) / lsum, fp32, fused normalize (no partials pass)
    gemm_out<<<dim3(256), dim3(512), 0, stream>>>(Sexp, Vt, lsum, out);
}

// Round 7
// 271.746 us; speedup vs baseline: 1.0006x; 1.0006x over previous
//
#include <hip/hip_runtime.h>

typedef __bf16 bf16x8 __attribute__((ext_vector_type(8)));
typedef float f32x4 __attribute__((ext_vector_type(4)));
typedef unsigned short us8 __attribute__((ext_vector_type(8)));

#define GAS __attribute__((address_space(1)))
#define LAS __attribute__((address_space(3)))

__device__ __forceinline__ unsigned short f32_to_bf16(float f) {
    unsigned int u = __float_as_uint(f);
    u += 0x7FFFu + ((u >> 16) & 1u);   // round-to-nearest-even
    return (unsigned short)(u >> 16);
}

__device__ __forceinline__ float bf16_to_f32(unsigned short h) {
    return __uint_as_float((unsigned int)h << 16);
}

__device__ __forceinline__ void load16(const unsigned short* g, unsigned short* l) {
    // async global->LDS, 16B per lane; LDS dest is wave-uniform base + lane*16
    __builtin_amdgcn_global_load_lds((GAS unsigned int*)g, (LAS unsigned int*)l, 16, 0, 0);
}

// ---------------------------------------------------------------------------
// prep (1024 threads): blocks [0,1536) convert x fp32->bf16 float4-wide;
// blocks [1536,3264) transpose the three 768x768 weights to bf16;
// block 3264 zeroes lsum[2*4096] (denominator accumulators).
// ---------------------------------------------------------------------------
__global__ __launch_bounds__(1024) void prep(
    const float* __restrict__ x, unsigned short* __restrict__ Xbf,
    const float* __restrict__ W0, const float* __restrict__ W1, const float* __restrict__ W2,
    unsigned short* __restrict__ T0, unsigned short* __restrict__ T1, unsigned short* __restrict__ T2,
    float* __restrict__ lsum)
{
    __shared__ float tile[32][33];
    const int id = blockIdx.x;
    const int t = threadIdx.x;
    if (id < 1536) {
        int i = id * 1024 + t;
        float4 v = ((const float4*)x)[i];
        ushort4 o;
        o.x = f32_to_bf16(v.x); o.y = f32_to_bf16(v.y);
        o.z = f32_to_bf16(v.z); o.w = f32_to_bf16(v.w);
        ((ushort4*)Xbf)[i] = o;
    } else if (id < 3264) {
        const int tid = id - 1536;               // 0..1727
        const int z = tid / 576, rem = tid % 576;
        const int by = rem / 24, bx = rem % 24;
        const float* W = (z == 0) ? W0 : (z == 1) ? W1 : W2;
        unsigned short* T = (z == 0) ? T0 : (z == 1) ? T1 : T2;
        const int r0 = by * 32, c0 = bx * 32;
        const int tx = t & 31, ty = t >> 5;      // 32x32
        tile[ty][tx] = W[(size_t)(r0 + ty) * 768 + c0 + tx];
        __syncthreads();
        T[(size_t)(c0 + ty) * 768 + r0 + tx] = f32_to_bf16(tile[tx][ty]);
    } else {
        float4 z4 = {0.f, 0.f, 0.f, 0.f};
        ((float4*)lsum)[t] = z4;
        ((float4*)lsum)[t + 1024] = z4;          // 8192 floats total
    }
}

// ---------------------------------------------------------------------------
// Combined Q/K/V projection (m97 structure + XOR bank-swizzle), one launch:
//   id <  768 : QK  -- C[z] = Xbf[8192,768] . (W^T[z])^T, z = id/384
//   id >= 768 : V^T -- Vt   = WvT[768,768]  . Xbf^T  -> [768, 8192]
// ---------------------------------------------------------------------------
__global__ __launch_bounds__(256) void qkv_proj(
    const unsigned short* __restrict__ Xbf,
    const unsigned short* __restrict__ Wt,
    unsigned short* __restrict__ QK,
    unsigned short* __restrict__ Vt)
{
    const int id = blockIdx.x;
    const unsigned short* A; const unsigned short* B;
    unsigned short* C; int ldc, m0, n0;
    if (id < 768) {
        const int z = id / 384, r = id % 384;
        A = Xbf; B = Wt + (size_t)z * 589824; C = QK + (size_t)z * 6291456;
        ldc = 768;
        m0 = (r / 6) * 128; n0 = (r % 6) * 128;
    } else {
        const int j = id - 768;
        A = Wt + 1179648ull;   // WvT
        B = Xbf; C = Vt;
        ldc = 8192;
        m0 = (j >> 6) * 128; n0 = (j & 63) * 128;
    }
    const int lda = 768, ldb = 768;
    const int t = threadIdx.x;
    const int lane = t & 63;
    const int w = t >> 6;
    const int wm = (w >> 1) * 64;
    const int wn = (w & 1) * 64;

    __shared__ unsigned short At[128 * 64];
    __shared__ unsigned short Bt[128 * 64];

    f32x4 acc[4][4];
#pragma unroll
    for (int i = 0; i < 4; ++i)
#pragma unroll
        for (int j2 = 0; j2 < 4; ++j2) acc[i][j2] = (f32x4){0.f, 0.f, 0.f, 0.f};

    const int r15 = lane & 15;
    const int qa = lane >> 4;

    for (int k0 = 0; k0 < 768; k0 += 64) {
#pragma unroll
        for (int i = 0; i < 4; ++i) {
            const int c = i * 256 + t;
            const int row = c >> 3;
            const int cc = (c & 7) ^ (row & 7);
            load16(A + (size_t)(m0 + row) * lda + k0 + cc * 8, &At[c * 8]);
            load16(B + (size_t)(n0 + row) * ldb + k0 + cc * 8, &Bt[c * 8]);
        }
        __syncthreads();

#pragma unroll
        for (int ks = 0; ks < 2; ++ks) {
            bf16x8 af[4], bf[4];
#pragma unroll
            for (int mi = 0; mi < 4; ++mi) {
                const int row = wm + mi * 16 + r15;
                af[mi] = *(const bf16x8*)&At[row * 64 + (((ks << 2) + qa) ^ (row & 7)) * 8];
            }
#pragma unroll
            for (int ni = 0; ni < 4; ++ni) {
                const int row = wn + ni * 16 + r15;
                bf[ni] = *(const bf16x8*)&Bt[row * 64 + (((ks << 2) + qa) ^ (row & 7)) * 8];
            }
#pragma unroll
            for (int mi = 0; mi < 4; ++mi)
#pragma unroll
                for (int ni = 0; ni < 4; ++ni)
                    acc[mi][ni] = __builtin_amdgcn_mfma_f32_16x16x32_bf16(
                        af[mi], bf[ni], acc[mi][ni], 0, 0, 0);
        }
        __syncthreads();
    }

    const int cr = (lane >> 4) * 4;
#pragma unroll
    for (int mi = 0; mi < 4; ++mi)
#pragma unroll
        for (int ni = 0; ni < 4; ++ni) {
            const int gm = m0 + wm + mi * 16 + cr;
            const int gn = n0 + wn + ni * 16 + r15;
#pragma unroll
            for (int r = 0; r < 4; ++r)
                C[(size_t)(gm + r) * ldc + gn] = f32_to_bf16(acc[mi][ni][r]);
        }
}

// ---------------------------------------------------------------------------
// Sexp = exp(alpha * Q.K^T) bf16, 256^2 v4 core (monolithic body, ring-2 LDS,
// counted vmcnt, 2 barriers/tile, XCD swizzle). Epilogue = R4's store-only
// form (low register pressure, no spill), THEN a zero-pressure row-sum pass:
// drain stores, barrier, each thread re-reads half a row of the block's own
// just-written tile (L2-hot, same XCD, never-before-read addresses so no
// stale L1), sums 128 bf16, one shfl pair-combine, one atomicAdd per row.
// ---------------------------------------------------------------------------
__global__ __launch_bounds__(512, 2) void gemm_s_exp2(
    const unsigned short* __restrict__ Q, const unsigned short* __restrict__ Kb,
    unsigned short* __restrict__ Sexp, float* __restrict__ lsum, float alpha)
{
    const int f = blockIdx.x;            // 0..511
    const int xcd = f & 7;
    const int local = f >> 3;            // 0..63
    const int x = (xcd & 1) * 8 + (local & 7);
    const int y = ((xcd >> 1) & 1) * 8 + (local >> 3);
    const int bb = xcd >> 2;
    const unsigned short* A = Q + (size_t)bb * 3145728;
    const unsigned short* B = Kb + (size_t)bb * 3145728;
    unsigned short* C = Sexp + (size_t)bb * 16777216;
    float* ls = lsum + bb * 4096;
    const int m0 = y * 256, n0 = x * 256;
    const int lda = 768, ldb = 768, ldc = 4096;
    constexpr int NT = 12;

    __shared__ unsigned short As[2][256 * 64];
    __shared__ unsigned short Bs[2][256 * 64];

    const int t = threadIdx.x;          // 0..511
    const int lane = t & 63;
    const int w = t >> 6;               // 0..7
    const int wm = (w >> 2) * 128;      // 0 / 128
    const int wn = (w & 3) * 64;        // 0..192
    const int r15 = lane & 15;
    const int qa = lane >> 4;           // 0..3

    const unsigned short* srcA[4];
    const unsigned short* srcB[4];
    int dst[4];
#pragma unroll
    for (int i = 0; i < 4; ++i) {
        const int c = i * 512 + t;
        const int row = c >> 3;
        const int cc = (c & 7) ^ (row & 7);
        srcA[i] = A + (size_t)(m0 + row) * lda + cc * 8;
        srcB[i] = B + (size_t)(n0 + row) * ldb + cc * 8;
        dst[i] = c * 8;
    }

    auto stage = [&](int buf, int kbase) {
#pragma unroll
        for (int i = 0; i < 4; ++i)
            load16(srcA[i] + kbase, &As[buf][dst[i]]);
#pragma unroll
        for (int i = 0; i < 4; ++i)
            load16(srcB[i] + kbase, &Bs[buf][dst[i]]);
    };

    int offA[8][2], offB[4][2];
#pragma unroll
    for (int mi = 0; mi < 8; ++mi) {
        const int row = wm + mi * 16 + r15;
#pragma unroll
        for (int ks = 0; ks < 2; ++ks)
            offA[mi][ks] = row * 64 + (((ks << 2) + qa) ^ (row & 7)) * 8;
    }
#pragma unroll
    for (int ni = 0; ni < 4; ++ni) {
        const int row = wn + ni * 16 + r15;
#pragma unroll
        for (int ks = 0; ks < 2; ++ks)
            offB[ni][ks] = row * 64 + (((ks << 2) + qa) ^ (row & 7)) * 8;
    }

    f32x4 acc[8][4];
#pragma unroll
    for (int i = 0; i < 8; ++i)
#pragma unroll
        for (int j = 0; j < 4; ++j) acc[i][j] = (f32x4){0.f, 0.f, 0.f, 0.f};

    stage(0, 0);
    stage(1, 64);

    for (int tt = 0; tt < NT; ++tt) {
        const int b = tt & 1;
        if (tt == NT - 1) {
            asm volatile("s_waitcnt vmcnt(0)" ::: "memory");
        } else {
            asm volatile("s_waitcnt vmcnt(8)" ::: "memory");
        }
        __builtin_amdgcn_s_barrier();

#pragma unroll
        for (int ks = 0; ks < 2; ++ks) {
            bf16x8 aA[8], bB[4];
#pragma unroll
            for (int i = 0; i < 8; ++i)
                aA[i] = *(const bf16x8*)&As[b][offA[i][ks]];
#pragma unroll
            for (int ni = 0; ni < 4; ++ni)
                bB[ni] = *(const bf16x8*)&Bs[b][offB[ni][ks]];
#pragma unroll
            for (int i = 0; i < 8; ++i)
#pragma unroll
                for (int ni = 0; ni < 4; ++ni)
                    acc[i][ni] = __builtin_amdgcn_mfma_f32_16x16x32_bf16(
                        aA[i], bB[ni], acc[i][ni], 0, 0, 0);
        }

        asm volatile("" ::: "memory");
        __builtin_amdgcn_s_barrier();

        if (tt + 2 < NT) stage(b, (tt + 2) << 6);
    }

    // store-only epilogue (R4 form, low register pressure)
    const int cr = (lane >> 4) * 4;
#pragma unroll
    for (int mi = 0; mi < 8; ++mi)
#pragma unroll
        for (int ni = 0; ni < 4; ++ni) {
            const int gm = m0 + wm + mi * 16 + cr;
            const int gn = n0 + wn + ni * 16 + r15;
#pragma unroll
            for (int r = 0; r < 4; ++r)
                C[(size_t)(gm + r) * ldc + gn] =
                    f32_to_bf16(__expf(alpha * acc[mi][ni][r]));
        }

    // row-sum pass: acc is dead here -> zero register-pressure conflict.
    asm volatile("s_waitcnt vmcnt(0)" ::: "memory");
    __builtin_amdgcn_s_barrier();

    {
        const int row = t >> 1;                       // 0..255
        const unsigned short* rp =
            C + (size_t)(m0 + row) * ldc + n0 + (t & 1) * 128;
        float s = 0.f;
#pragma unroll
        for (int i = 0; i < 16; ++i) {
            us8 v = ((const us8*)rp)[i];
#pragma unroll
            for (int j = 0; j < 8; ++j) s += bf16_to_f32(v[j]);
        }
        s += __shfl_xor(s, 1, 64);                    // combine the two halves
        if ((t & 1) == 0) atomicAdd(&ls[m0 + row], s);
    }
}

// ---------------------------------------------------------------------------
// Fused O-GEMM + normalize: out = (Sexp . V) / lsum, fp32, single K=4096
// chain. BM=128 x BN=192 -> 256 blocks = exact one round. Ring-3 LDS,
// counted vmcnt(10/5/0). 8 waves 2M x 4N, per-wave 64x48 (acc[4][3]).
// XCD swizzle: xcd = batch*4 + nb -> each XCD keeps ONE V^T panel L2-resident.
// ---------------------------------------------------------------------------
__global__ __launch_bounds__(512, 2) void gemm_out(
    const unsigned short* __restrict__ P, const unsigned short* __restrict__ Vt,
    const float* __restrict__ lsum, float* __restrict__ out)
{
    const int f = blockIdx.x;           // 0..255
    const int xcd = f & 7;
    const int batch = xcd >> 2;
    const int nb = xcd & 3;
    const int mb = f >> 3;              // 0..31
    const unsigned short* A = P + (size_t)batch * 16777216;
    const unsigned short* B = Vt + (size_t)batch * 4096;
    const float* ls = lsum + batch * 4096;
    float* C = out + (size_t)batch * 3145728;
    const int m0 = mb * 128, n0 = nb * 192;
    const int lda = 4096, ldb = 8192;
    constexpr int NT = 64;

    __shared__ unsigned short As[3][128 * 64];
    __shared__ unsigned short Bs[3][192 * 64];

    const int t = threadIdx.x;          // 0..511
    const int lane = t & 63;
    const int w = t >> 6;               // 0..7
    const int wm = (w >> 2) * 64;       // 0 / 64
    const int wn = (w & 3) * 48;        // 0..144
    const int r15 = lane & 15;
    const int qa = lane >> 4;           // 0..3

    const unsigned short* srcA[2];
    int dstA[2];
#pragma unroll
    for (int i = 0; i < 2; ++i) {
        const int c = i * 512 + t;
        const int row = c >> 3;
        const int cc = (c & 7) ^ (row & 7);
        srcA[i] = A + (size_t)(m0 + row) * lda + cc * 8;
        dstA[i] = c * 8;
    }
    const unsigned short* srcB[3];
    int dstB[3];
#pragma unroll
    for (int i = 0; i < 3; ++i) {
        const int c = i * 512 + t;
        const int row = c >> 3;
        const int cc = (c & 7) ^ (row & 7);
        srcB[i] = B + (size_t)(n0 + row) * ldb + cc * 8;
        dstB[i] = c * 8;
    }

    auto stage = [&](int buf, int kbase) {
#pragma unroll
        for (int i = 0; i < 2; ++i)
            load16(srcA[i] + kbase, &As[buf][dstA[i]]);
#pragma unroll
        for (int i = 0; i < 3; ++i)
            load16(srcB[i] + kbase, &Bs[buf][dstB[i]]);
    };

    int offA[4][2], offB[3][2];
#pragma unroll
    for (int mi = 0; mi < 4; ++mi) {
        const int row = wm + mi * 16 + r15;
#pragma unroll
        for (int ks = 0; ks < 2; ++ks)
            offA[mi][ks] = row * 64 + (((ks << 2) + qa) ^ (row & 7)) * 8;
    }
#pragma unroll
    for (int ni = 0; ni < 3; ++ni) {
        const int row = wn + ni * 16 + r15;
#pragma unroll
        for (int ks = 0; ks < 2; ++ks)
            offB[ni][ks] = row * 64 + (((ks << 2) + qa) ^ (row & 7)) * 8;
    }

    f32x4 acc[4][3];
#pragma unroll
    for (int i = 0; i < 4; ++i)
#pragma unroll
        for (int j = 0; j < 3; ++j) acc[i][j] = (f32x4){0.f, 0.f, 0.f, 0.f};

    stage(0, 0);
    stage(1, 64);
    stage(2, 128);

    int b = 0;
    for (int tt = 0; tt < NT; ++tt) {
        if (tt < NT - 2) {
            asm volatile("s_waitcnt vmcnt(10)" ::: "memory");
        } else if (tt == NT - 2) {
            asm volatile("s_waitcnt vmcnt(5)" ::: "memory");
        } else {
            asm volatile("s_waitcnt vmcnt(0)" ::: "memory");
        }
        __builtin_amdgcn_s_barrier();

#pragma unroll
        for (int ks = 0; ks < 2; ++ks) {
            bf16x8 aA[4], bB[3];
#pragma unroll
            for (int i = 0; i < 4; ++i)
                aA[i] = *(const bf16x8*)&As[b][offA[i][ks]];
#pragma unroll
            for (int ni = 0; ni < 3; ++ni)
                bB[ni] = *(const bf16x8*)&Bs[b][offB[ni][ks]];
#pragma unroll
            for (int i = 0; i < 4; ++i)
#pragma unroll
                for (int ni = 0; ni < 3; ++ni)
                    acc[i][ni] = __builtin_amdgcn_mfma_f32_16x16x32_bf16(
                        aA[i], bB[ni], acc[i][ni], 0, 0, 0);
        }

        asm volatile("" ::: "memory");
        __builtin_amdgcn_s_barrier();

        if (tt + 3 < NT) stage(b, (tt + 3) << 6);
        b = (b == 2) ? 0 : b + 1;
    }

    // epilogue: divide by denominator, write fp32 out
    const int cr = (lane >> 4) * 4;
#pragma unroll
    for (int mi = 0; mi < 4; ++mi) {
        const int gm = m0 + wm + mi * 16 + cr;
        const float i0 = 1.f / ls[gm + 0];
        const float i1 = 1.f / ls[gm + 1];
        const float i2 = 1.f / ls[gm + 2];
        const float i3 = 1.f / ls[gm + 3];
#pragma unroll
        for (int ni = 0; ni < 3; ++ni) {
            const int gn = n0 + wn + ni * 16 + r15;
            C[(size_t)(gm + 0) * 768 + gn] = acc[mi][ni][0] * i0;
            C[(size_t)(gm + 1) * 768 + gn] = acc[mi][ni][1] * i1;
            C[(size_t)(gm + 2) * 768 + gn] = acc[mi][ni][2] * i2;
            C[(size_t)(gm + 3) * 768 + gn] = acc[mi][ni][3] * i3;
        }
    }
}

// ---------------------------------------------------------------------------
extern "C" void kernel_launch(void* const* d_in, const int* in_sizes, int n_in,
                              void* d_out, int out_size, void* d_ws, size_t ws_size,
                              hipStream_t stream) {
    const float* x  = (const float*)d_in[0];   // [2,4096,768]
    const float* Wq = (const float*)d_in[1];   // [768,768]
    const float* Wk = (const float*)d_in[2];
    const float* Wv = (const float*)d_in[3];
    float* out = (float*)d_out;                // [2,4096,768] fp32

    char* base = (char*)d_ws;
    size_t off = 0;
    auto alloc = [&](size_t b) { char* p = base + off; off += (b + 255) & ~(size_t)255; return p; };

    unsigned short* Xbf = (unsigned short*)alloc(8192ull * 768 * 2);   // x as bf16
    unsigned short* WqT = (unsigned short*)alloc(768ull * 768 * 2);    // W^T bf16, x3 contiguous
    unsigned short* WkT = (unsigned short*)alloc(768ull * 768 * 2);
    unsigned short* WvT = (unsigned short*)alloc(768ull * 768 * 2);
    unsigned short* Qb  = (unsigned short*)alloc(8192ull * 768 * 2);   // Q,K bf16, contiguous
    unsigned short* Kb  = (unsigned short*)alloc(8192ull * 768 * 2);
    unsigned short* Vt  = (unsigned short*)alloc(768ull * 8192 * 2);   // V^T bf16 [768,8192]
    unsigned short* Sexp = (unsigned short*)alloc(2ull * 4096 * 4096 * 2); // exp(scores) bf16
    float* lsum = (float*)alloc(2ull * 4096 * 4);                      // softmax denominators
    (void)ws_size; (void)in_sizes; (void)n_in; (void)out_size; (void)WkT; (void)WvT;

    // 1) x -> bf16, W -> W^T bf16, lsum <- 0
    prep<<<dim3(3265), dim3(1024), 0, stream>>>(x, Xbf, Wq, Wk, Wv, WqT, WkT, WvT, lsum);
    // 2) Q, K and V^T in ONE launch (1152 blocks)
    qkv_proj<<<dim3(1152), dim3(256), 0, stream>>>(Xbf, WqT, Qb, Vt);
    // 3) Sexp = exp(Q.K^T / sqrt(768)) bf16 + low-pressure fused row sums
    gemm_s_exp2<<<dim3(512), dim3(512), 0, stream>>>(
        Qb, Kb, Sexp, lsum, 0.03608439182435161f);
    // 4) out = (Sexp . V) / lsum, fp32, fused normalize
    gemm_out<<<dim3(256), dim3(512), 0, stream>>>(Sexp, Vt, lsum, out);
}

// Round 8
// 249.957 us; speedup vs baseline: 1.0878x; 1.0872x over previous
//
#include <hip/hip_runtime.h>

typedef __bf16 bf16x8 __attribute__((ext_vector_type(8)));
typedef float f32x4 __attribute__((ext_vector_type(4)));
typedef unsigned short us8 __attribute__((ext_vector_type(8)));

#define GAS __attribute__((address_space(1)))
#define LAS __attribute__((address_space(3)))

__device__ __forceinline__ unsigned short f32_to_bf16(float f) {
    unsigned int u = __float_as_uint(f);
    u += 0x7FFFu + ((u >> 16) & 1u);   // round-to-nearest-even
    return (unsigned short)(u >> 16);
}

__device__ __forceinline__ float bf16_to_f32(unsigned short h) {
    return __uint_as_float((unsigned int)h << 16);
}

__device__ __forceinline__ void load16(const unsigned short* g, unsigned short* l) {
    // async global->LDS, 16B per lane; LDS dest is wave-uniform base + lane*16
    __builtin_amdgcn_global_load_lds((GAS unsigned int*)g, (LAS unsigned int*)l, 16, 0, 0);
}

// ---------------------------------------------------------------------------
// prep (1024 threads): blocks [0,1536) convert x fp32->bf16 float4-wide;
// blocks [1536,3264) transpose the three 768x768 weights to bf16.
// ---------------------------------------------------------------------------
__global__ __launch_bounds__(1024) void prep(
    const float* __restrict__ x, unsigned short* __restrict__ Xbf,
    const float* __restrict__ W0, const float* __restrict__ W1, const float* __restrict__ W2,
    unsigned short* __restrict__ T0, unsigned short* __restrict__ T1, unsigned short* __restrict__ T2)
{
    __shared__ float tile[32][33];
    const int id = blockIdx.x;
    const int t = threadIdx.x;
    if (id < 1536) {
        int i = id * 1024 + t;
        float4 v = ((const float4*)x)[i];
        ushort4 o;
        o.x = f32_to_bf16(v.x); o.y = f32_to_bf16(v.y);
        o.z = f32_to_bf16(v.z); o.w = f32_to_bf16(v.w);
        ((ushort4*)Xbf)[i] = o;
    } else {
        const int tid = id - 1536;               // 0..1727
        const int z = tid / 576, rem = tid % 576;
        const int by = rem / 24, bx = rem % 24;
        const float* W = (z == 0) ? W0 : (z == 1) ? W1 : W2;
        unsigned short* T = (z == 0) ? T0 : (z == 1) ? T1 : T2;
        const int r0 = by * 32, c0 = bx * 32;
        const int tx = t & 31, ty = t >> 5;      // 32x32
        tile[ty][tx] = W[(size_t)(r0 + ty) * 768 + c0 + tx];
        __syncthreads();
        T[(size_t)(c0 + ty) * 768 + r0 + tx] = f32_to_bf16(tile[tx][ty]);
    }
}

// ---------------------------------------------------------------------------
// Combined Q/K/V projection (m97 structure + XOR bank-swizzle), one launch:
//   id <  768 : QK  -- C[z] = Xbf[8192,768] . (W^T[z])^T, z = id/384
//   id >= 768 : V^T -- Vt   = WvT[768,768]  . Xbf^T  -> [768, 8192]
// ---------------------------------------------------------------------------
__global__ __launch_bounds__(256) void qkv_proj(
    const unsigned short* __restrict__ Xbf,
    const unsigned short* __restrict__ Wt,
    unsigned short* __restrict__ QK,
    unsigned short* __restrict__ Vt)
{
    const int id = blockIdx.x;
    const unsigned short* A; const unsigned short* B;
    unsigned short* C; int ldc, m0, n0;
    if (id < 768) {
        const int z = id / 384, r = id % 384;
        A = Xbf; B = Wt + (size_t)z * 589824; C = QK + (size_t)z * 6291456;
        ldc = 768;
        m0 = (r / 6) * 128; n0 = (r % 6) * 128;
    } else {
        const int j = id - 768;
        A = Wt + 1179648ull;   // WvT
        B = Xbf; C = Vt;
        ldc = 8192;
        m0 = (j >> 6) * 128; n0 = (j & 63) * 128;
    }
    const int lda = 768, ldb = 768;
    const int t = threadIdx.x;
    const int lane = t & 63;
    const int w = t >> 6;
    const int wm = (w >> 1) * 64;
    const int wn = (w & 1) * 64;

    __shared__ unsigned short At[128 * 64];
    __shared__ unsigned short Bt[128 * 64];

    f32x4 acc[4][4];
#pragma unroll
    for (int i = 0; i < 4; ++i)
#pragma unroll
        for (int j2 = 0; j2 < 4; ++j2) acc[i][j2] = (f32x4){0.f, 0.f, 0.f, 0.f};

    const int r15 = lane & 15;
    const int qa = lane >> 4;

    for (int k0 = 0; k0 < 768; k0 += 64) {
#pragma unroll
        for (int i = 0; i < 4; ++i) {
            const int c = i * 256 + t;
            const int row = c >> 3;
            const int cc = (c & 7) ^ (row & 7);
            load16(A + (size_t)(m0 + row) * lda + k0 + cc * 8, &At[c * 8]);
            load16(B + (size_t)(n0 + row) * ldb + k0 + cc * 8, &Bt[c * 8]);
        }
        __syncthreads();

#pragma unroll
        for (int ks = 0; ks < 2; ++ks) {
            bf16x8 af[4], bf[4];
#pragma unroll
            for (int mi = 0; mi < 4; ++mi) {
                const int row = wm + mi * 16 + r15;
                af[mi] = *(const bf16x8*)&At[row * 64 + (((ks << 2) + qa) ^ (row & 7)) * 8];
            }
#pragma unroll
            for (int ni = 0; ni < 4; ++ni) {
                const int row = wn + ni * 16 + r15;
                bf[ni] = *(const bf16x8*)&Bt[row * 64 + (((ks << 2) + qa) ^ (row & 7)) * 8];
            }
#pragma unroll
            for (int mi = 0; mi < 4; ++mi)
#pragma unroll
                for (int ni = 0; ni < 4; ++ni)
                    acc[mi][ni] = __builtin_amdgcn_mfma_f32_16x16x32_bf16(
                        af[mi], bf[ni], acc[mi][ni], 0, 0, 0);
        }
        __syncthreads();
    }

    const int cr = (lane >> 4) * 4;
#pragma unroll
    for (int mi = 0; mi < 4; ++mi)
#pragma unroll
        for (int ni = 0; ni < 4; ++ni) {
            const int gm = m0 + wm + mi * 16 + cr;
            const int gn = n0 + wn + ni * 16 + r15;
#pragma unroll
            for (int r = 0; r < 4; ++r)
                C[(size_t)(gm + r) * ldc + gn] = f32_to_bf16(acc[mi][ni][r]);
        }
}

// ---------------------------------------------------------------------------
// Sexp = exp(alpha * Q.K^T) bf16, 256^2 v4 core (monolithic body, ring-2 LDS,
// counted vmcnt, 2 barriers/tile, XCD swizzle). Store-only epilogue (the R4
// form measured at 60.6 us) -- NO fused row sums (both fused variants lost
// ~20 us: R5 in-register pressure, R7 HBM readback tail).
// ---------------------------------------------------------------------------
__global__ __launch_bounds__(512, 2) void gemm_s_exp2(
    const unsigned short* __restrict__ Q, const unsigned short* __restrict__ Kb,
    unsigned short* __restrict__ Sexp, float alpha)
{
    const int f = blockIdx.x;            // 0..511
    const int xcd = f & 7;
    const int local = f >> 3;            // 0..63
    const int x = (xcd & 1) * 8 + (local & 7);
    const int y = ((xcd >> 1) & 1) * 8 + (local >> 3);
    const int bb = xcd >> 2;
    const unsigned short* A = Q + (size_t)bb * 3145728;
    const unsigned short* B = Kb + (size_t)bb * 3145728;
    unsigned short* C = Sexp + (size_t)bb * 16777216;
    const int m0 = y * 256, n0 = x * 256;
    const int lda = 768, ldb = 768, ldc = 4096;
    constexpr int NT = 12;

    __shared__ unsigned short As[2][256 * 64];
    __shared__ unsigned short Bs[2][256 * 64];

    const int t = threadIdx.x;          // 0..511
    const int lane = t & 63;
    const int w = t >> 6;               // 0..7
    const int wm = (w >> 2) * 128;      // 0 / 128
    const int wn = (w & 3) * 64;        // 0..192
    const int r15 = lane & 15;
    const int qa = lane >> 4;           // 0..3

    const unsigned short* srcA[4];
    const unsigned short* srcB[4];
    int dst[4];
#pragma unroll
    for (int i = 0; i < 4; ++i) {
        const int c = i * 512 + t;
        const int row = c >> 3;
        const int cc = (c & 7) ^ (row & 7);
        srcA[i] = A + (size_t)(m0 + row) * lda + cc * 8;
        srcB[i] = B + (size_t)(n0 + row) * ldb + cc * 8;
        dst[i] = c * 8;
    }

    auto stage = [&](int buf, int kbase) {
#pragma unroll
        for (int i = 0; i < 4; ++i)
            load16(srcA[i] + kbase, &As[buf][dst[i]]);
#pragma unroll
        for (int i = 0; i < 4; ++i)
            load16(srcB[i] + kbase, &Bs[buf][dst[i]]);
    };

    int offA[8][2], offB[4][2];
#pragma unroll
    for (int mi = 0; mi < 8; ++mi) {
        const int row = wm + mi * 16 + r15;
#pragma unroll
        for (int ks = 0; ks < 2; ++ks)
            offA[mi][ks] = row * 64 + (((ks << 2) + qa) ^ (row & 7)) * 8;
    }
#pragma unroll
    for (int ni = 0; ni < 4; ++ni) {
        const int row = wn + ni * 16 + r15;
#pragma unroll
        for (int ks = 0; ks < 2; ++ks)
            offB[ni][ks] = row * 64 + (((ks << 2) + qa) ^ (row & 7)) * 8;
    }

    f32x4 acc[8][4];
#pragma unroll
    for (int i = 0; i < 8; ++i)
#pragma unroll
        for (int j = 0; j < 4; ++j) acc[i][j] = (f32x4){0.f, 0.f, 0.f, 0.f};

    stage(0, 0);
    stage(1, 64);

    for (int tt = 0; tt < NT; ++tt) {
        const int b = tt & 1;
        if (tt == NT - 1) {
            asm volatile("s_waitcnt vmcnt(0)" ::: "memory");
        } else {
            asm volatile("s_waitcnt vmcnt(8)" ::: "memory");
        }
        __builtin_amdgcn_s_barrier();

#pragma unroll
        for (int ks = 0; ks < 2; ++ks) {
            bf16x8 aA[8], bB[4];
#pragma unroll
            for (int i = 0; i < 8; ++i)
                aA[i] = *(const bf16x8*)&As[b][offA[i][ks]];
#pragma unroll
            for (int ni = 0; ni < 4; ++ni)
                bB[ni] = *(const bf16x8*)&Bs[b][offB[ni][ks]];
#pragma unroll
            for (int i = 0; i < 8; ++i)
#pragma unroll
                for (int ni = 0; ni < 4; ++ni)
                    acc[i][ni] = __builtin_amdgcn_mfma_f32_16x16x32_bf16(
                        aA[i], bB[ni], acc[i][ni], 0, 0, 0);
        }

        asm volatile("" ::: "memory");
        __builtin_amdgcn_s_barrier();

        if (tt + 2 < NT) stage(b, (tt + 2) << 6);
    }

    // store-only epilogue (low register pressure)
    const int cr = (lane >> 4) * 4;
#pragma unroll
    for (int mi = 0; mi < 8; ++mi)
#pragma unroll
        for (int ni = 0; ni < 4; ++ni) {
            const int gm = m0 + wm + mi * 16 + cr;
            const int gn = n0 + wn + ni * 16 + r15;
#pragma unroll
            for (int r = 0; r < 4; ++r)
                C[(size_t)(gm + r) * ldc + gn] =
                    f32_to_bf16(__expf(alpha * acc[mi][ni][r]));
        }
}

// ---------------------------------------------------------------------------
// Fused O-GEMM + normalize: out = (Sexp . V) / rowsum(Sexp), fp32.
// Row sums via the ones-vector MFMA trick: acc1[mi] = mfma(aA[mi], 1, acc1[mi])
// accumulates sum_k A[row,k] in every D column; the D layout
// (row=(lane>>4)*4+reg) hands each thread exactly the denominators for the
// 4 rows it writes -- zero communication, no atomics, no extra pass.
// BM=128 x BN=192 -> 256 blocks = exact one round. Ring-3 LDS, counted
// vmcnt(10/5/0). XCD swizzle (FIXED): the 4 n-blocks of one (batch,mb)
// row group share an XCD -> each Sexp tile is fetched from HBM once and
// L2-hit 3x (per-k-tile set: 8x16KB A + 96KB Vt << 4MB L2).
// ---------------------------------------------------------------------------
__global__ __launch_bounds__(512, 2) void gemm_out(
    const unsigned short* __restrict__ P, const unsigned short* __restrict__ Vt,
    float* __restrict__ out)
{
    const int f = blockIdx.x;           // 0..255
    const int xcd = f & 7;              // hw: consecutive ids round-robin XCDs
    const int local = f >> 3;           // 0..31
    const int nb = local & 3;           // n-block 0..3 (same XCD for all 4)
    const int rg = xcd * 8 + (local >> 2);   // row group 0..63
    const int batch = rg >> 5;
    const int mb = rg & 31;             // m-block 0..31
    const unsigned short* A = P + (size_t)batch * 16777216;
    const unsigned short* B = Vt + (size_t)batch * 4096;
    float* C = out + (size_t)batch * 3145728;
    const int m0 = mb * 128, n0 = nb * 192;
    const int lda = 4096, ldb = 8192;
    constexpr int NT = 64;

    __shared__ unsigned short As[3][128 * 64];
    __shared__ unsigned short Bs[3][192 * 64];

    const int t = threadIdx.x;          // 0..511
    const int lane = t & 63;
    const int w = t >> 6;               // 0..7
    const int wm = (w >> 2) * 64;       // 0 / 64
    const int wn = (w & 3) * 48;        // 0..144
    const int r15 = lane & 15;
    const int qa = lane >> 4;           // 0..3

    const unsigned short* srcA[2];
    int dstA[2];
#pragma unroll
    for (int i = 0; i < 2; ++i) {
        const int c = i * 512 + t;
        const int row = c >> 3;
        const int cc = (c & 7) ^ (row & 7);
        srcA[i] = A + (size_t)(m0 + row) * lda + cc * 8;
        dstA[i] = c * 8;
    }
    const unsigned short* srcB[3];
    int dstB[3];
#pragma unroll
    for (int i = 0; i < 3; ++i) {
        const int c = i * 512 + t;
        const int row = c >> 3;
        const int cc = (c & 7) ^ (row & 7);
        srcB[i] = B + (size_t)(n0 + row) * ldb + cc * 8;
        dstB[i] = c * 8;
    }

    auto stage = [&](int buf, int kbase) {
#pragma unroll
        for (int i = 0; i < 2; ++i)
            load16(srcA[i] + kbase, &As[buf][dstA[i]]);
#pragma unroll
        for (int i = 0; i < 3; ++i)
            load16(srcB[i] + kbase, &Bs[buf][dstB[i]]);
    };

    int offA[4][2], offB[3][2];
#pragma unroll
    for (int mi = 0; mi < 4; ++mi) {
        const int row = wm + mi * 16 + r15;
#pragma unroll
        for (int ks = 0; ks < 2; ++ks)
            offA[mi][ks] = row * 64 + (((ks << 2) + qa) ^ (row & 7)) * 8;
    }
#pragma unroll
    for (int ni = 0; ni < 3; ++ni) {
        const int row = wn + ni * 16 + r15;
#pragma unroll
        for (int ks = 0; ks < 2; ++ks)
            offB[ni][ks] = row * 64 + (((ks << 2) + qa) ^ (row & 7)) * 8;
    }

    // constant all-ones B fragment (bf16 1.0 = 0x3F80)
    us8 uo;
#pragma unroll
    for (int j = 0; j < 8; ++j) uo[j] = 0x3F80;
    const bf16x8 vones = __builtin_bit_cast(bf16x8, uo);

    f32x4 acc[4][3];
    f32x4 acc1[4];                      // row sums (every column identical)
#pragma unroll
    for (int i = 0; i < 4; ++i) {
#pragma unroll
        for (int j = 0; j < 3; ++j) acc[i][j] = (f32x4){0.f, 0.f, 0.f, 0.f};
        acc1[i] = (f32x4){0.f, 0.f, 0.f, 0.f};
    }

    stage(0, 0);
    stage(1, 64);
    stage(2, 128);

    int b = 0;
    for (int tt = 0; tt < NT; ++tt) {
        if (tt < NT - 2) {
            asm volatile("s_waitcnt vmcnt(10)" ::: "memory");
        } else if (tt == NT - 2) {
            asm volatile("s_waitcnt vmcnt(5)" ::: "memory");
        } else {
            asm volatile("s_waitcnt vmcnt(0)" ::: "memory");
        }
        __builtin_amdgcn_s_barrier();

#pragma unroll
        for (int ks = 0; ks < 2; ++ks) {
            bf16x8 aA[4], bB[3];
#pragma unroll
            for (int i = 0; i < 4; ++i)
                aA[i] = *(const bf16x8*)&As[b][offA[i][ks]];
#pragma unroll
            for (int ni = 0; ni < 3; ++ni)
                bB[ni] = *(const bf16x8*)&Bs[b][offB[ni][ks]];
#pragma unroll
            for (int i = 0; i < 4; ++i) {
#pragma unroll
                for (int ni = 0; ni < 3; ++ni)
                    acc[i][ni] = __builtin_amdgcn_mfma_f32_16x16x32_bf16(
                        aA[i], bB[ni], acc[i][ni], 0, 0, 0);
                acc1[i] = __builtin_amdgcn_mfma_f32_16x16x32_bf16(
                    aA[i], vones, acc1[i], 0, 0, 0);
            }
        }

        asm volatile("" ::: "memory");
        __builtin_amdgcn_s_barrier();

        if (tt + 3 < NT) stage(b, (tt + 3) << 6);
        b = (b == 2) ? 0 : b + 1;
    }

    // epilogue: divide by in-register denominator, write fp32 out
    const int cr = (lane >> 4) * 4;
#pragma unroll
    for (int mi = 0; mi < 4; ++mi) {
        const int gm = m0 + wm + mi * 16 + cr;
        const float i0 = 1.f / acc1[mi][0];
        const float i1 = 1.f / acc1[mi][1];
        const float i2 = 1.f / acc1[mi][2];
        const float i3 = 1.f / acc1[mi][3];
#pragma unroll
        for (int ni = 0; ni < 3; ++ni) {
            const int gn = n0 + wn + ni * 16 + r15;
            C[(size_t)(gm + 0) * 768 + gn] = acc[mi][ni][0] * i0;
            C[(size_t)(gm + 1) * 768 + gn] = acc[mi][ni][1] * i1;
            C[(size_t)(gm + 2) * 768 + gn] = acc[mi][ni][2] * i2;
            C[(size_t)(gm + 3) * 768 + gn] = acc[mi][ni][3] * i3;
        }
    }
}

// ---------------------------------------------------------------------------
extern "C" void kernel_launch(void* const* d_in, const int* in_sizes, int n_in,
                              void* d_out, int out_size, void* d_ws, size_t ws_size,
                              hipStream_t stream) {
    const float* x  = (const float*)d_in[0];   // [2,4096,768]
    const float* Wq = (const float*)d_in[1];   // [768,768]
    const float* Wk = (const float*)d_in[2];
    const float* Wv = (const float*)d_in[3];
    float* out = (float*)d_out;                // [2,4096,768] fp32

    char* base = (char*)d_ws;
    size_t off = 0;
    auto alloc = [&](size_t b) { char* p = base + off; off += (b + 255) & ~(size_t)255; return p; };

    unsigned short* Xbf = (unsigned short*)alloc(8192ull * 768 * 2);   // x as bf16
    unsigned short* WqT = (unsigned short*)alloc(768ull * 768 * 2);    // W^T bf16, x3 contiguous
    unsigned short* WkT = (unsigned short*)alloc(768ull * 768 * 2);
    unsigned short* WvT = (unsigned short*)alloc(768ull * 768 * 2);
    unsigned short* Qb  = (unsigned short*)alloc(8192ull * 768 * 2);   // Q,K bf16, contiguous
    unsigned short* Kb  = (unsigned short*)alloc(8192ull * 768 * 2);
    unsigned short* Vt  = (unsigned short*)alloc(768ull * 8192 * 2);   // V^T bf16 [768,8192]
    unsigned short* Sexp = (unsigned short*)alloc(2ull * 4096 * 4096 * 2); // exp(scores) bf16
    (void)ws_size; (void)in_sizes; (void)n_in; (void)out_size; (void)WkT; (void)WvT;

    // 1) x -> bf16, W -> W^T bf16
    prep<<<dim3(3264), dim3(1024), 0, stream>>>(x, Xbf, Wq, Wk, Wv, WqT, WkT, WvT);
    // 2) Q, K and V^T in ONE launch (1152 blocks)
    qkv_proj<<<dim3(1152), dim3(256), 0, stream>>>(Xbf, WqT, Qb, Vt);
    // 3) Sexp = exp(Q.K^T / sqrt(768)) bf16 (store-only epilogue, R4 form)
    gemm_s_exp2<<<dim3(512), dim3(512), 0, stream>>>(
        Qb, Kb, Sexp, 0.03608439182435161f);
    // 4) out = (Sexp . V) / rowsum(Sexp), fp32 -- ones-MFMA denominator,
    //    row-sharing XCD swizzle
    gemm_out<<<dim3(256), dim3(512), 0, stream>>>(Sexp, Vt, out);
}